// Round 12
// baseline (649.592 us; speedup 1.0000x reference)
//
#include <hip/hip_runtime.h>

#define B_ 8
#define T_ 2048
#define C_ 1024
#define H_ 16
#define HD_ 64
#define BH_ (B_ * H_)
#define M_ (B_ * T_)

typedef __attribute__((ext_vector_type(8))) short short8;
typedef __attribute__((ext_vector_type(4))) float floatx4;
typedef __attribute__((ext_vector_type(16))) float floatx16;

__device__ __forceinline__ short f2bf(float f) {
  unsigned int u = __float_as_uint(f);
  u += 0x7fffu + ((u >> 16) & 1u);
  return (short)(u >> 16);
}

// one-instruction packed f32x2 -> bf16x2 (RNE)
__device__ __forceinline__ unsigned cvtpk(float a, float b) {
  unsigned r;
  asm("v_cvt_pk_bf16_f32 %0, %1, %2" : "=v"(r) : "v"(a), "v"(b));
  return r;
}

// raw v_exp_f32: computes 2^x
__device__ __forceinline__ float ex2(float x) {
  float r;
  asm("v_exp_f32 %0, %1" : "=v"(r) : "v"(x));
  return r;
}

__device__ __forceinline__ void g2lds16(const void* g, void* l) {
  __builtin_amdgcn_global_load_lds(
      (const __attribute__((address_space(1))) unsigned int*)g,
      (__attribute__((address_space(3))) unsigned int*)l, 16, 0, 0);
}

// ---------------------------------------------------------------- converters
__global__ void cvt_x_kernel(const float* __restrict__ x, short* __restrict__ xb, int n8) {
  int i = blockIdx.x * 256 + threadIdx.x;
  if (i >= n8) return;
  const float4* p = reinterpret_cast<const float4*>(x) + (size_t)i * 2;
  float4 a = p[0], b = p[1];
  short8 o;
  o[0] = f2bf(a.x); o[1] = f2bf(a.y); o[2] = f2bf(a.z); o[3] = f2bf(a.w);
  o[4] = f2bf(b.x); o[5] = f2bf(b.y); o[6] = f2bf(b.z); o[7] = f2bf(b.w);
  reinterpret_cast<short8*>(xb)[i] = o;
}

// transpose f32 W[K][N] -> bf16 Wt[N][K], 64x64 tiles, 256 threads
__global__ void transpose_w_kernel(const float* __restrict__ W, short* __restrict__ Wt,
                                   int K, int N) {
  __shared__ float tile[64][65];
  const int k0 = blockIdx.y * 64;
  const int n0 = blockIdx.x * 64;
  const int tid = threadIdx.x;
  const int cc = tid & 15, rr = tid >> 4;
#pragma unroll
  for (int p = 0; p < 4; ++p) {
    int r = p * 16 + rr;
    float4 v = *reinterpret_cast<const float4*>(&W[(size_t)(k0 + r) * N + n0 + cc * 4]);
    tile[r][cc * 4 + 0] = v.x; tile[r][cc * 4 + 1] = v.y;
    tile[r][cc * 4 + 2] = v.z; tile[r][cc * 4 + 3] = v.w;
  }
  __syncthreads();
  const int kk8 = tid & 7, nn = tid >> 3;
#pragma unroll
  for (int p = 0; p < 2; ++p) {
    int n = p * 32 + nn;
    short8 o;
#pragma unroll
    for (int j = 0; j < 8; ++j) o[j] = f2bf(tile[kk8 * 8 + j][n]);
    *reinterpret_cast<short8*>(&Wt[(size_t)(n0 + n) * K + k0 + kk8 * 8]) = o;
  }
}

__global__ void trig_kernel(const float* __restrict__ freqs, float2* __restrict__ cs, int n) {
  int i = blockIdx.x * 256 + threadIdx.x;
  if (i < n) {
    float f = freqs[i];
    cs[i] = make_float2(cosf(f), sinf(f));
  }
}

// ---------------------------------------------------------------- 256x256 4-wave GEMM
// 4 waves, each owns a 128x128 output (acc 8x8 f32x4 in unified VGPR/AGPR).
// Rationale: GEMM is LDS-read-port bound; 64 ds_read_b128/tile/CU (770cy) for
// the same MFMA work (vs 96-128 reads in 8/16-wave variants). Ring of 4 LDS
// tile slots (32KB) staged 3 ahead, counted vmcnt (8 loads/thread/tile ->
// WAIT16 steady, 8/0 tail), one raw barrier per tile, frag-prefetch pipeline.
#define WAIT16 asm volatile("s_waitcnt vmcnt(16)" ::: "memory")
#define WAIT8  asm volatile("s_waitcnt vmcnt(8)" ::: "memory")
#define WAIT4  asm volatile("s_waitcnt vmcnt(4)" ::: "memory")
#define WAIT2  asm volatile("s_waitcnt vmcnt(2)" ::: "memory")
#define WAIT0  asm volatile("s_waitcnt vmcnt(0)" ::: "memory")

#define GITER(T, CUR, NXT)                                                        \
  {                                                                               \
    const int tbR = ((T) & 3) << 15;                                              \
    /* phase A: prefetch A(T, mh=1), MFMA mh=0 */                                 \
    _Pragma("unroll") for (int i = 0; i < 4; ++i)                                 \
        af1[i] = *reinterpret_cast<const short8*>(ldsb + tbR + aoff[4 + i]);      \
    __builtin_amdgcn_s_setprio(1);                                                \
    _Pragma("unroll") for (int m = 0; m < 4; ++m)                                 \
        _Pragma("unroll") for (int n = 0; n < 8; ++n)                             \
            acc[m][n] = __builtin_amdgcn_mfma_f32_16x16x32_bf16(                  \
                af0[m], CUR[n], acc[m][n], 0, 0, 0);                              \
    __builtin_amdgcn_s_setprio(0);                                                \
    /* phase B: stage, counted wait, drain DS, barrier, prefetch t+1, MFMA mh=1 */\
    if ((T) + 3 < NT) { stageA((T) + 3); stageB((T) + 3); }                       \
    if ((T) < NT - 3) { WAIT16; }                                                 \
    else if ((T) == NT - 3) { WAIT8; }                                            \
    else if ((T) == NT - 2) { WAIT0; }                                            \
    asm volatile("s_waitcnt lgkmcnt(0)" ::: "memory");                            \
    __builtin_amdgcn_s_barrier();                                                 \
    if ((T) + 1 < NT) {                                                           \
      const int tbN = (((T) + 1) & 3) << 15;                                      \
      _Pragma("unroll") for (int n = 0; n < 8; ++n)                               \
          NXT[n] = *reinterpret_cast<const short8*>(ldsb + tbN + boff[n]);        \
      _Pragma("unroll") for (int i = 0; i < 4; ++i)                               \
          af0[i] = *reinterpret_cast<const short8*>(ldsb + tbN + aoff[i]);        \
    }                                                                             \
    __builtin_amdgcn_s_setprio(1);                                                \
    _Pragma("unroll") for (int m = 0; m < 4; ++m)                                 \
        _Pragma("unroll") for (int n = 0; n < 8; ++n)                             \
            acc[4 + m][n] = __builtin_amdgcn_mfma_f32_16x16x32_bf16(              \
                af1[m], CUR[n], acc[4 + m][n], 0, 0, 0);                          \
    __builtin_amdgcn_s_setprio(0);                                                \
  }

template <int EPI>
__global__ __launch_bounds__(256, 1) void gemm4_kernel(
    const short* __restrict__ A, const short* __restrict__ Bt,
    const float* __restrict__ bias, int Ndim, int nbx, float* __restrict__ outF,
    short* __restrict__ Qw, short* __restrict__ Kw, short* __restrict__ Vw,
    const float2* __restrict__ trig) {
  constexpr int Kd = 1024, NT = 32;
  __shared__ short lds[65536];  // 4 slots x 32KB (A 16KB + B 16KB)
  const char* ldsb = reinterpret_cast<const char*>(lds);
  const int tid = threadIdx.x, l = tid & 63, w = tid >> 6;  // 4 waves
  const int wr = w >> 1, wc = w & 1;  // wave output: rows wr*128, cols wc*128

  // level 1: bijective XCD-chunked swizzle (gridDim.x % 8 == 0)
  const int nwg = gridDim.x, qq8 = nwg >> 3;
  const int bid = blockIdx.x;
  const int wg = (bid & 7) * qq8 + (bid >> 3);
  // level 2: 4x4 patches of 16 consecutive wg (nbx % 4 == 0, nby % 4 == 0)
  const int npx = nbx >> 2;
  const int p = wg >> 4, q = wg & 15;
  const int bx = (p % npx) * 4 + (q & 3);
  const int by = (p / npx) * 4 + (q >> 2);
  const int m0 = by * 256, n0 = bx * 256;

  // staging: thread stages chunks {tid + 256*i, i=0..3} of each 16KB half.
  // chunk c: super c>>3, slot c&7; logical lc = slot ^ (super&7); since
  // 256*i keeps (super&7) invariant, lc is i-invariant; row = i*64 + rowS_b.
  const int sup_b = tid >> 3;
  const int lcS = (tid & 7) ^ (sup_b & 7);
  const int rowS_b = 2 * sup_b + (lcS >> 2);
  const int colS = (lcS & 3) << 3;
  const short* aRow[4];
  const short* bRow[4];
#pragma unroll
  for (int i = 0; i < 4; ++i) {
    aRow[i] = &A[(size_t)(m0 + i * 64 + rowS_b) * Kd + colS];
    bRow[i] = &Bt[(size_t)(n0 + i * 64 + rowS_b) * Kd + colS];
  }

  // fragment read constants: row = (wr|wc)*128 + idx*16 + cl;
  // super = row>>1, slot = (((cl&1)<<2)+r4h) ^ (super&7)
  const int cl = l & 15, r4h = l >> 4;
  const int supL = cl >> 1;
  const int aslot = (((cl & 1) << 2) + r4h) ^ supL;
  int aoff[8], boff[8];
#pragma unroll
  for (int m = 0; m < 8; ++m)
    aoff[m] = (wr * 64 + m * 8 + supL) * 128 + aslot * 16;
#pragma unroll
  for (int n = 0; n < 8; ++n)
    boff[n] = 16384 + (wc * 64 + n * 8 + supL) * 128 + aslot * 16;

  auto stageA = [&](int t) {
    const int sb = (t & 3) << 15;
#pragma unroll
    for (int i = 0; i < 4; ++i)
      g2lds16(aRow[i] + t * 32, (char*)lds + sb + i * 4096 + tid * 16);
  };
  auto stageB = [&](int t) {
    const int sb = ((t & 3) << 15) + 16384;
#pragma unroll
    for (int i = 0; i < 4; ++i)
      g2lds16(bRow[i] + t * 32, (char*)lds + sb + i * 4096 + tid * 16);
  };

  floatx4 acc[8][8] = {};
  short8 af0[4], af1[4], bbA[8], bbB[8];

  // prologue: stage tiles 0..2 (24 loads), drain to tile 0, read frags(0)
  stageA(0); stageB(0);
  stageA(1); stageB(1);
  stageA(2); stageB(2);
  WAIT16;
  __builtin_amdgcn_s_barrier();
#pragma unroll
  for (int n = 0; n < 8; ++n)
    bbA[n] = *reinterpret_cast<const short8*>(ldsb + boff[n]);
#pragma unroll
  for (int i = 0; i < 4; ++i)
    af0[i] = *reinterpret_cast<const short8*>(ldsb + aoff[i]);

  for (int t = 0; t < NT; t += 2) {
    GITER(t, bbA, bbB);
    GITER(t + 1, bbB, bbA);
  }

  // ---------------- epilogue: D layout col=lane&15, row=(lane>>4)*4+r
  const int r4 = r4h * 4;
  if (EPI == 0 && n0 >= 2048) {
    // V blocks: per-wave LDS transpose (16KB region: 64 d x 128 t bf16,
    // 16 slots/row, slot-XOR swizzled) -> coalesced Vt[bh][d][t] stores.
    // Two per-head passes (wave covers 128 d-cols = 2 heads). Regions use
    // slots 0-1 (<=64KB); last ring reads were slot 3 -> no barrier needed.
    short* vr = &lds[w * 8192];
    const int t0g = (m0 & 2047) + wr * 128;
#pragma unroll
    for (int hp = 0; hp < 2; ++hp) {
      const int hh = ((n0 - 2048) >> 6) + wc * 2 + hp;
      const int bhv = (m0 >> 11) * 16 + hh;
#pragma unroll
      for (int m = 0; m < 8; ++m) {
#pragma unroll
        for (int n = 0; n < 4; ++n) {
          const int gn = n0 + wc * 128 + hp * 64 + n * 16 + cl;
          const float bs = bias[gn];
          const int d = n * 16 + cl;
          const int sW = m * 2 + (r4h >> 1);
          const int byte = d * 256 + ((sW ^ (d & 15)) << 4) + ((r4h & 1) << 3);
          uint2 pv;
          pv.x = cvtpk(acc[m][hp * 4 + n][0] + bs, acc[m][hp * 4 + n][1] + bs);
          pv.y = cvtpk(acc[m][hp * 4 + n][2] + bs, acc[m][hp * 4 + n][3] + bs);
          *reinterpret_cast<uint2*>(reinterpret_cast<char*>(vr) + byte) = pv;
        }
      }
#pragma unroll
      for (int g = 0; g < 16; ++g) {
        const int d = g * 4 + r4h;
        const int byte = d * 256 + ((cl ^ (d & 15)) << 4);
        short8 vv = *reinterpret_cast<const short8*>(
            reinterpret_cast<const char*>(vr) + byte);
        *reinterpret_cast<short8*>(
            &Vw[((size_t)bhv * 64 + d) * 2048 + t0g + cl * 8]) = vv;
      }
    }
  } else {
#pragma unroll
    for (int m = 0; m < 8; ++m) {
#pragma unroll
      for (int n = 0; n < 8; ++n) {
        const int gn = n0 + wc * 128 + n * 16 + cl;
#pragma unroll
        for (int r = 0; r < 4; ++r) {
          const int gm = m0 + wr * 128 + m * 16 + r4 + r;
          float v = acc[m][n][r] + bias[gn];
          if (EPI == 1) {
            outF[(size_t)gm * Ndim + gn] = v;
          } else {
            const int b = gm >> 11, t = gm & 2047;
            const int ccol = gn & 1023;
            const int h = ccol >> 6, d = ccol & 63;
            const int bh = b * 16 + h;
            float2 cs = trig[t * 32 + (d >> 1)];
            float p2 = __shfl_xor(v, 1);
            float o = (d & 1) ? (p2 * cs.y + v * cs.x) : (v * cs.x - p2 * cs.y);
            if ((gn >> 10) == 0) {
              // fold 1/sqrt(64) * log2(e): softmax done in exp2 domain
              Qw[((size_t)bh * T_ + t) * HD_ + d] = f2bf(o * 0.18033688011112042f);
            } else {
              Kw[((size_t)bh * T_ + t) * HD_ + d] = f2bf(o);
            }
          }
        }
      }
    }
  }
}

// ---------------------------------------------------------------- flash attention
// KVBLK=64: ring of 3 KV LDS buffers (16KB each) staged 2 tiles ahead; ONE raw
// s_barrier + ONE counted vmcnt per 64 keys. Swapped QK^T via mfma_32x32x16 in
// two independent 32-key halves. FIXED-max softmax: scores bounded, accumulator
// initialized to -16 (C-operand, free) -> ex2 directly, no max tracking or
// rescale. Diagonal tile: even waves skip the fully-masked upper half.
__global__ __launch_bounds__(256) void attn_kernel(
    const short* __restrict__ Q, const short* __restrict__ Kw,
    const short* __restrict__ Vt, short* __restrict__ Y) {
  __shared__ short lds[3][8192];  // per buf: K 4096 shorts + V 2x2048 shorts
  const int tid = threadIdx.x, l = tid & 63, w = tid >> 6;
  const int ql = l & 31, hi = l >> 5;
  const int bh = blockIdx.x;
  const int qb = 15 - (int)blockIdx.y;
  const int q0w = qb * 128 + w * 32;       // this wave's first query row
  const int jlast = 2 * qb + (w >> 1);     // last KV tile this wave needs
  const int nj = 2 * qb + 2;               // KV tiles staged by the block (>=2)

  short8 qf[4];
  {
    const size_t qbase = ((size_t)bh * T_ + q0w + ql) * HD_;
#pragma unroll
    for (int s = 0; s < 4; ++s)
      qf[s] = *reinterpret_cast<const short8*>(&Q[qbase + s * 16 + hi * 8]);
  }

  // hoisted LDS read offsets (shorts)
  int koffs[4], voffs[4];
#pragma unroll
  for (int s = 0; s < 4; ++s)
    koffs[s] = ql * 64 + (((2 * s + hi) ^ (ql & 7)) * 8);
#pragma unroll
  for (int s2 = 0; s2 < 2; ++s2)
#pragma unroll
    for (int h = 0; h < 2; ++h) {
      int r = 16 * h + (ql >> 1);
      int lc = (ql & 1) * 4 + 2 * s2 + hi;
      voffs[s2 * 2 + h] = r * 64 + ((lc ^ (r & 7)) * 8);
    }

  // staging pointers (advance per tile)
  const int rowSt = tid >> 3, pSt = tid & 7;
  const int gkSt = pSt ^ (rowSt & 7);
  const int dvSt = 2 * rowSt + (gkSt >> 2), kcSt = gkSt & 3;
  const short* kg0 = &Kw[((size_t)bh * T_ + rowSt) * HD_ + gkSt * 8];
  const short* kg1 = &Kw[((size_t)bh * T_ + rowSt + 32) * HD_ + gkSt * 8];
  const short* vg0 = &Vt[((size_t)bh * HD_ + dvSt) * T_ + kcSt * 8];
  const short* vg1 = vg0 + 32;

  floatx16 o0 = {}, o1 = {};
  float l_run = 0.f;

#define STAGE_KV(buf)                                   \
  {                                                     \
    g2lds16(kg0, &lds[buf][0] + tid * 8);               \
    g2lds16(kg1, &lds[buf][2048] + tid * 8);            \
    g2lds16(vg0, &lds[buf][4096] + tid * 8);            \
    g2lds16(vg1, &lds[buf][6144] + tid * 8);            \
    kg0 += 64 * HD_; kg1 += 64 * HD_;                   \
    vg0 += 64; vg1 += 64;                               \
  }

  auto do_half = [&](const short* bK, const short* bV, int koff_add, int vbase,
                     bool domask) {
    floatx16 sx;
#pragma unroll
    for (int r = 0; r < 16; ++r) sx[r] = -16.0f;  // fixed-max offset
#pragma unroll
    for (int s = 0; s < 4; ++s) {
      short8 ka = *reinterpret_cast<const short8*>(bK + koff_add + koffs[s]);
      sx = __builtin_amdgcn_mfma_f32_32x32x16_bf16(ka, qf[s], sx, 0, 0, 0);
    }
    if (domask) {
#pragma unroll
      for (int r = 0; r < 16; ++r) {
        int kb = (r & 3) + 8 * (r >> 2) + 4 * hi;
        if (kb > ql) sx[r] = -1e30f;
      }
    }
#pragma unroll
    for (int r = 0; r < 16; ++r) sx[r] = ex2(sx[r]);
    float a0 = (sx[0] + sx[1]) + (sx[2] + sx[3]);
    float a1 = (sx[4] + sx[5]) + (sx[6] + sx[7]);
    float a2 = (sx[8] + sx[9]) + (sx[10] + sx[11]);
    float a3 = (sx[12] + sx[13]) + (sx[14] + sx[15]);
    l_run += (a0 + a1) + (a2 + a3);
    unsigned pw[8];
#pragma unroll
    for (int i = 0; i < 8; ++i) pw[i] = cvtpk(sx[2 * i], sx[2 * i + 1]);
#pragma unroll
    for (int s2 = 0; s2 < 2; ++s2) {
      unsigned a0w = pw[4 * s2 + 0], a1w = pw[4 * s2 + 1];
      unsigned a2w = pw[4 * s2 + 2], a3w = pw[4 * s2 + 3];
      asm("v_permlane32_swap_b32 %0, %1" : "+v"(a0w), "+v"(a2w));
      asm("v_permlane32_swap_b32 %0, %1" : "+v"(a1w), "+v"(a3w));
      union { unsigned u[4]; short8 s8; } pb;
      pb.u[0] = a0w; pb.u[1] = a1w; pb.u[2] = a2w; pb.u[3] = a3w;
#pragma unroll
      for (int h = 0; h < 2; ++h) {
        short8 va = *reinterpret_cast<const short8*>(bV + vbase + voffs[s2 * 2 + h]);
        if (h == 0) o0 = __builtin_amdgcn_mfma_f32_32x32x16_bf16(va, pb.s8, o0, 0, 0, 0);
        else        o1 = __builtin_amdgcn_mfma_f32_32x32x16_bf16(va, pb.s8, o1, 0, 0, 0);
      }
    }
  };

  STAGE_KV(0);
  STAGE_KV(1);

  for (int j = 0; j < nj; ++j) {
    if (j == nj - 1) { WAIT0; } else { WAIT4; }
    __builtin_amdgcn_s_barrier();
    if (j + 2 < nj) STAGE_KV((j + 2) % 3);

    if (j <= jlast) {
      const short* bK = &lds[j % 3][0];
      const short* bV = &lds[j % 3][4096];
      const bool diag = (j == jlast);
      do_half(bK, bV, 0, 0, diag && ((w & 1) == 0));
      if (!diag || (w & 1))
        do_half(bK, bV, 2048, 2048, diag);
    }
  }

  l_run += __shfl_xor(l_run, 32);
  float inv = 1.0f / l_run;
#pragma unroll
  for (int r = 0; r < 16; ++r) { o0[r] *= inv; o1[r] *= inv; }
  __syncthreads();
  short* tb2 = &lds[0][0] + w * 2048;
#pragma unroll
  for (int h = 0; h < 2; ++h) {
#pragma unroll
    for (int qd = 0; qd < 4; ++qd) {
      int dbase = 32 * h + 8 * qd + 4 * hi;
      uint2 v;
      v.x = h == 0 ? cvtpk(o0[4 * qd], o0[4 * qd + 1]) : cvtpk(o1[4 * qd], o1[4 * qd + 1]);
      v.y = h == 0 ? cvtpk(o0[4 * qd + 2], o0[4 * qd + 3]) : cvtpk(o1[4 * qd + 2], o1[4 * qd + 3]);
      int byte = (ql * 128 + dbase * 2) ^ ((ql & 7) << 4);
      *reinterpret_cast<uint2*>(reinterpret_cast<char*>(tb2) + byte) = v;
    }
  }
  __syncthreads();
  const int bb = bh >> 4, hh = bh & 15;
#pragma unroll
  for (int p = 0; p < 4; ++p) {
    int c = p * 64 + l;
    int q = c >> 3, dc = c & 7;
    int byte = (q * 128 + dc * 16) ^ ((q & 7) << 4);
    short8 v = *reinterpret_cast<const short8*>(reinterpret_cast<const char*>(tb2) + byte);
    *reinterpret_cast<short8*>(
        &Y[((size_t)(bb * T_ + q0w + q)) * C_ + hh * 64 + dc * 8]) = v;
  }
#undef STAGE_KV
}

// ---------------------------------------------------------------- launch
extern "C" void kernel_launch(void* const* d_in, const int* in_sizes, int n_in,
                              void* d_out, int out_size, void* d_ws, size_t ws_size,
                              hipStream_t stream) {
  const float* x      = (const float*)d_in[0];
  const float* freqs  = (const float*)d_in[1];
  const float* W_attn = (const float*)d_in[2];
  const float* b_attn = (const float*)d_in[3];
  const float* W_proj = (const float*)d_in[4];
  const float* b_proj = (const float*)d_in[5];
  float* out = (float*)d_out;
  char* ws = (char*)d_ws;

  const size_t SZ_QKV = (size_t)BH_ * T_ * HD_ * 2;  // 33554432 bytes each
  short* Qw  = (short*)(ws);
  short* Kw  = (short*)(ws + SZ_QKV);
  short* Vt  = (short*)(ws + 2 * SZ_QKV);
  short* Xb  = (short*)(ws + 3 * SZ_QKV);            // x bf16, later reused as Y
  short* WtA = (short*)(ws + 4 * SZ_QKV);            // [3072][1024] bf16
  short* WtP = (short*)(ws + 4 * SZ_QKV + 6291456);  // [1024][1024] bf16
  float2* trig = (float2*)(ws + 4 * SZ_QKV + 6291456 + 2097152);  // [2048][32]

  cvt_x_kernel<<<(M_ * C_ / 8 + 255) / 256, 256, 0, stream>>>(x, Xb, M_ * C_ / 8);
  transpose_w_kernel<<<dim3(3 * C_ / 64, C_ / 64), 256, 0, stream>>>(W_attn, WtA, C_, 3 * C_);
  transpose_w_kernel<<<dim3(C_ / 64, C_ / 64), 256, 0, stream>>>(W_proj, WtP, C_, C_);
  trig_kernel<<<(T_ * 32 + 255) / 256, 256, 0, stream>>>(freqs, trig, T_ * 32);

  gemm4_kernel<0><<<dim3((3 * C_ / 256) * (M_ / 256)), 256, 0, stream>>>(
      Xb, WtA, b_attn, 3 * C_, 3 * C_ / 256, nullptr, Qw, Kw, Vt, trig);

  attn_kernel<<<dim3(BH_, 16), 256, 0, stream>>>(Qw, Kw, Vt, Xb);

  gemm4_kernel<1><<<dim3((C_ / 256) * (M_ / 256)), 256, 0, stream>>>(
      Xb, WtP, b_proj, C_, C_ / 256, out, nullptr, nullptr, nullptr, nullptr);
}

// Round 13
// 275.119 us; speedup vs baseline: 2.3611x; 2.3611x over previous
//
#include <hip/hip_runtime.h>

#define B_ 8
#define T_ 2048
#define C_ 1024
#define H_ 16
#define HD_ 64
#define BH_ (B_ * H_)
#define M_ (B_ * T_)

typedef __attribute__((ext_vector_type(8))) short short8;
typedef __attribute__((ext_vector_type(4))) float floatx4;
typedef __attribute__((ext_vector_type(16))) float floatx16;

__device__ __forceinline__ short f2bf(float f) {
  unsigned int u = __float_as_uint(f);
  u += 0x7fffu + ((u >> 16) & 1u);
  return (short)(u >> 16);
}

// one-instruction packed f32x2 -> bf16x2 (RNE)
__device__ __forceinline__ unsigned cvtpk(float a, float b) {
  unsigned r;
  asm("v_cvt_pk_bf16_f32 %0, %1, %2" : "=v"(r) : "v"(a), "v"(b));
  return r;
}

// raw v_exp_f32: computes 2^x
__device__ __forceinline__ float ex2(float x) {
  float r;
  asm("v_exp_f32 %0, %1" : "=v"(r) : "v"(x));
  return r;
}

__device__ __forceinline__ void g2lds16(const void* g, void* l) {
  __builtin_amdgcn_global_load_lds(
      (const __attribute__((address_space(1))) unsigned int*)g,
      (__attribute__((address_space(3))) unsigned int*)l, 16, 0, 0);
}

// ---------------------------------------------------------------- converters
__global__ void cvt_x_kernel(const float* __restrict__ x, short* __restrict__ xb, int n8) {
  int i = blockIdx.x * 256 + threadIdx.x;
  if (i >= n8) return;
  const float4* p = reinterpret_cast<const float4*>(x) + (size_t)i * 2;
  float4 a = p[0], b = p[1];
  short8 o;
  o[0] = f2bf(a.x); o[1] = f2bf(a.y); o[2] = f2bf(a.z); o[3] = f2bf(a.w);
  o[4] = f2bf(b.x); o[5] = f2bf(b.y); o[6] = f2bf(b.z); o[7] = f2bf(b.w);
  reinterpret_cast<short8*>(xb)[i] = o;
}

// transpose f32 W[K][N] -> bf16 Wt[N][K], 64x64 tiles, 256 threads
__global__ void transpose_w_kernel(const float* __restrict__ W, short* __restrict__ Wt,
                                   int K, int N) {
  __shared__ float tile[64][65];
  const int k0 = blockIdx.y * 64;
  const int n0 = blockIdx.x * 64;
  const int tid = threadIdx.x;
  const int cc = tid & 15, rr = tid >> 4;
#pragma unroll
  for (int p = 0; p < 4; ++p) {
    int r = p * 16 + rr;
    float4 v = *reinterpret_cast<const float4*>(&W[(size_t)(k0 + r) * N + n0 + cc * 4]);
    tile[r][cc * 4 + 0] = v.x; tile[r][cc * 4 + 1] = v.y;
    tile[r][cc * 4 + 2] = v.z; tile[r][cc * 4 + 3] = v.w;
  }
  __syncthreads();
  const int kk8 = tid & 7, nn = tid >> 3;
#pragma unroll
  for (int p = 0; p < 2; ++p) {
    int n = p * 32 + nn;
    short8 o;
#pragma unroll
    for (int j = 0; j < 8; ++j) o[j] = f2bf(tile[kk8 * 8 + j][n]);
    *reinterpret_cast<short8*>(&Wt[(size_t)(n0 + n) * K + k0 + kk8 * 8]) = o;
  }
}

__global__ void trig_kernel(const float* __restrict__ freqs, float2* __restrict__ cs, int n) {
  int i = blockIdx.x * 256 + threadIdx.x;
  if (i < n) {
    float f = freqs[i];
    cs[i] = make_float2(cosf(f), sinf(f));
  }
}

// ---------------------------------------------------------------- 256x256 8-wave GEMM (r10 verified)
// Pipelined fragments + ring of 4 LDS tile slots staged 3 ahead; 2-level block
// swizzle (XCD chunk + 4x4 patch). QKV epilogue: bias + RoPE -> Q,K; V -> Vt.
#define WAIT8 asm volatile("s_waitcnt vmcnt(8)" ::: "memory")
#define WAIT6 asm volatile("s_waitcnt vmcnt(6)" ::: "memory")
#define WAIT4 asm volatile("s_waitcnt vmcnt(4)" ::: "memory")
#define WAIT3 asm volatile("s_waitcnt vmcnt(3)" ::: "memory")
#define WAIT2 asm volatile("s_waitcnt vmcnt(2)" ::: "memory")
#define WAIT0 asm volatile("s_waitcnt vmcnt(0)" ::: "memory")

#define GITER(T, CUR, NXT)                                                        \
  {                                                                               \
    const int tbR = ((T) & 3) << 15;                                              \
    /* phase A: prefetch A(T, mh=1), MFMA mh=0 */                                 \
    _Pragma("unroll") for (int i = 0; i < 4; ++i)                                 \
        af1[i] = *reinterpret_cast<const short8*>(ldsb + tbR + aoff[4 + i]);      \
    __builtin_amdgcn_s_setprio(1);                                                \
    _Pragma("unroll") for (int m = 0; m < 4; ++m)                                 \
        _Pragma("unroll") for (int n = 0; n < 4; ++n)                             \
            acc[m][n] = __builtin_amdgcn_mfma_f32_16x16x32_bf16(                  \
                af0[m], CUR[n], acc[m][n], 0, 0, 0);                              \
    __builtin_amdgcn_s_setprio(0);                                                \
    /* phase B: stage, counted wait, drain DS, barrier, prefetch t+1, MFMA mh=1 */\
    if ((T) + 3 < NT) { stageA((T) + 3); stageB((T) + 3); }                       \
    if ((T) < NT - 3) { WAIT8; }                                                  \
    else if ((T) == NT - 3) { WAIT4; }                                            \
    else if ((T) == NT - 2) { WAIT0; }                                            \
    asm volatile("s_waitcnt lgkmcnt(0)" ::: "memory");                            \
    __builtin_amdgcn_s_barrier();                                                 \
    if ((T) + 1 < NT) {                                                           \
      const int tbN = (((T) + 1) & 3) << 15;                                      \
      _Pragma("unroll") for (int n = 0; n < 4; ++n)                               \
          NXT[n] = *reinterpret_cast<const short8*>(ldsb + tbN + boff[n]);        \
      _Pragma("unroll") for (int i = 0; i < 4; ++i)                               \
          af0[i] = *reinterpret_cast<const short8*>(ldsb + tbN + aoff[i]);        \
    }                                                                             \
    __builtin_amdgcn_s_setprio(1);                                                \
    _Pragma("unroll") for (int m = 0; m < 4; ++m)                                 \
        _Pragma("unroll") for (int n = 0; n < 4; ++n)                             \
            acc[4 + m][n] = __builtin_amdgcn_mfma_f32_16x16x32_bf16(              \
                af1[m], CUR[n], acc[4 + m][n], 0, 0, 0);                          \
    __builtin_amdgcn_s_setprio(0);                                                \
  }

__global__ __launch_bounds__(512, 2) void gemm8_kernel(
    const short* __restrict__ A, const short* __restrict__ Bt,
    const float* __restrict__ bias, int Ndim, int nbx,
    short* __restrict__ Qw, short* __restrict__ Kw, short* __restrict__ Vw,
    const float2* __restrict__ trig) {
  constexpr int Kd = 1024, NT = 32;
  __shared__ short lds[65536];  // 4 slots x 32KB
  const char* ldsb = reinterpret_cast<const char*>(lds);
  const int tid = threadIdx.x, l = tid & 63, w = tid >> 6;
  const int wr = w >> 2, wc = w & 3;

  // level 1: bijective XCD-chunked swizzle (gridDim.x % 8 == 0)
  const int nwg = gridDim.x, qq8 = nwg >> 3;
  const int bid = blockIdx.x;
  const int wg = (bid & 7) * qq8 + (bid >> 3);
  // level 2: 4x4 patches of 16 consecutive wg (nbx % 4 == 0, nby % 4 == 0)
  const int npx = nbx >> 2;
  const int p = wg >> 4, q = wg & 15;
  const int bx = (p % npx) * 4 + (q & 3);
  const int by = (p / npx) * 4 + (q >> 2);
  const int m0 = by * 256, n0 = bx * 256;

  // staging constants (paired-row layout + XOR swizzle, matches read side)
  const int sup1 = tid >> 3;
  const int lcS = (tid & 7) ^ (sup1 & 7);
  const int rowS = 2 * sup1 + (lcS >> 2);
  const int colS = (lcS & 3) << 3;

  // fragment read constants
  const int cl = l & 15, r4h = l >> 4;
  const int supL = cl >> 1;
  const int aslot = (((cl & 1) << 2) + r4h) ^ supL;
  int aoff[8], boff[4];
#pragma unroll
  for (int m = 0; m < 8; ++m)
    aoff[m] = (wr * 64 + m * 8 + supL) * 128 + aslot * 16;
#pragma unroll
  for (int n = 0; n < 4; ++n)
    boff[n] = 16384 + (wc * 32 + n * 8 + supL) * 128 + aslot * 16;

  auto stageA = [&](int t) {
    const int sb = (t & 3) << 15;
    const int k0 = t * 32;
    g2lds16(&A[(size_t)(m0 + rowS) * Kd + k0 + colS], (char*)lds + sb + tid * 16);
    g2lds16(&A[(size_t)(m0 + rowS + 128) * Kd + k0 + colS],
            (char*)lds + sb + 8192 + tid * 16);
  };
  auto stageB = [&](int t) {
    const int sb = ((t & 3) << 15) + 16384;
    const int k0 = t * 32;
    g2lds16(&Bt[(size_t)(n0 + rowS) * Kd + k0 + colS], (char*)lds + sb + tid * 16);
    g2lds16(&Bt[(size_t)(n0 + rowS + 128) * Kd + k0 + colS],
            (char*)lds + sb + 8192 + tid * 16);
  };

  floatx4 acc[8][4] = {};
  short8 af0[4], af1[4], bbA[4], bbB[4];

  // prologue: stage tiles 0..2, drain to tile 0, read frags(0)
  stageA(0); stageB(0);
  stageA(1); stageB(1);
  stageA(2); stageB(2);
  WAIT8;
  __builtin_amdgcn_s_barrier();
#pragma unroll
  for (int n = 0; n < 4; ++n)
    bbA[n] = *reinterpret_cast<const short8*>(ldsb + boff[n]);
#pragma unroll
  for (int i = 0; i < 4; ++i)
    af0[i] = *reinterpret_cast<const short8*>(ldsb + aoff[i]);

  for (int t = 0; t < NT; t += 2) {
    GITER(t, bbA, bbB);
    GITER(t + 1, bbB, bbA);
  }

  // ---------------- epilogue: D layout col=lane&15, row=(lane>>4)*4+r
  const int r4 = r4h * 4;
  if (n0 >= 2048) {
    // V blocks: LDS transpose -> coalesced Vt[bh][d][t] stores.
    short* vr = &lds[w * 8192];
    const int hh = ((n0 - 2048) >> 6) + wc;
    const int bhv = (m0 >> 11) * 16 + hh;
    const int t0g = (m0 & 2047) + wr * 128;
#pragma unroll
    for (int m = 0; m < 8; ++m) {
#pragma unroll
      for (int n = 0; n < 4; ++n) {
        const int gn = n0 + wc * 64 + n * 16 + cl;
        const float bs = bias[gn];
        const int d = n * 16 + cl;
        const int sW = m * 2 + (r4h >> 1);
        const int byte = d * 256 + (((sW ^ (d & 15))) << 4) + ((r4h & 1) << 3);
        uint2 pv;
        pv.x = cvtpk(acc[m][n][0] + bs, acc[m][n][1] + bs);
        pv.y = cvtpk(acc[m][n][2] + bs, acc[m][n][3] + bs);
        *reinterpret_cast<uint2*>(reinterpret_cast<char*>(vr) + byte) = pv;
      }
    }
#pragma unroll
    for (int g = 0; g < 16; ++g) {
      const int d = g * 4 + r4h;
      const int byte = d * 256 + (((cl ^ (d & 15))) << 4);
      short8 vv = *reinterpret_cast<const short8*>(
          reinterpret_cast<const char*>(vr) + byte);
      *reinterpret_cast<short8*>(&Vw[((size_t)bhv * 64 + d) * 2048 + t0g + cl * 8]) = vv;
    }
  } else {
#pragma unroll
    for (int m = 0; m < 8; ++m) {
#pragma unroll
      for (int n = 0; n < 4; ++n) {
        const int gn = n0 + wc * 64 + n * 16 + cl;
#pragma unroll
        for (int r = 0; r < 4; ++r) {
          const int gm = m0 + wr * 128 + m * 16 + r4 + r;
          float v = acc[m][n][r] + bias[gn];
          const int b = gm >> 11, t = gm & 2047;
          const int ccol = gn & 1023;
          const int h = ccol >> 6, d = ccol & 63;
          const int bh = b * 16 + h;
          float2 cs = trig[t * 32 + (d >> 1)];
          float p2 = __shfl_xor(v, 1);
          float o = (d & 1) ? (p2 * cs.y + v * cs.x) : (v * cs.x - p2 * cs.y);
          if ((gn >> 10) == 0) {
            // fold 1/sqrt(64) * log2(e): softmax done in exp2 domain
            Qw[((size_t)bh * T_ + t) * HD_ + d] = f2bf(o * 0.18033688011112042f);
          } else {
            Kw[((size_t)bh * T_ + t) * HD_ + d] = f2bf(o);
          }
        }
      }
    }
  }
}

// ---------------------------------------------------------------- 256x128 proj GEMM
// BM=256 x BN=128 tile -> grid 8x32 = 256 blocks = exactly 1/CU (the 256^2
// proj only filled 128 of 256 CUs). Same pipeline: ring of 4 slots (24KB:
// A 16KB + B 8KB), staged 3 ahead, 3 loads/thread/tile -> steady vmcnt(6),
// tail 3/0. 8 waves as 4x2, per-wave 64x64 output (acc[4][4]).
__global__ __launch_bounds__(512, 1) void gemm_proj_kernel(
    const short* __restrict__ A, const short* __restrict__ Bt,
    const float* __restrict__ bias, float* __restrict__ outF) {
  constexpr int Kd = 1024, NT = 32, Nd = 1024;
  __shared__ short lds[49152];  // 4 slots x 24KB
  const char* ldsb = reinterpret_cast<const char*>(lds);
  const int tid = threadIdx.x, l = tid & 63, w = tid >> 6;
  const int wr = w >> 1, wc = w & 1;  // wave output: rows wr*64, cols wc*64

  // level 1: XCD chunk (grid 256 % 8 == 0); level 2: 4x4 patches (nbx=8)
  const int nwg = gridDim.x, qq8 = nwg >> 3;
  const int bid = blockIdx.x;
  const int wg = (bid & 7) * qq8 + (bid >> 3);
  const int p = wg >> 4, q = wg & 15;
  const int bx = (p % 2) * 4 + (q & 3);        // 0..7
  const int by = (p / 2) * 4 + (q >> 2);       // 0..31
  const int m0 = by * 256, n0 = bx * 128;

  // staging constants (paired-row + XOR swizzle). A: chunks tid, tid+512
  // (rows rowS, rowS+128); B: chunk tid (rows 0..127).
  const int sup1 = tid >> 3;
  const int lcS = (tid & 7) ^ (sup1 & 7);
  const int rowS = 2 * sup1 + (lcS >> 2);
  const int colS = (lcS & 3) << 3;

  // fragment read constants
  const int cl = l & 15, r4h = l >> 4;
  const int supL = cl >> 1;
  const int aslot = (((cl & 1) << 2) + r4h) ^ supL;
  int aoff[4], boff[4];
#pragma unroll
  for (int m = 0; m < 4; ++m)
    aoff[m] = (wr * 32 + m * 8 + supL) * 128 + aslot * 16;
#pragma unroll
  for (int n = 0; n < 4; ++n)
    boff[n] = 16384 + (wc * 32 + n * 8 + supL) * 128 + aslot * 16;

  auto stageA = [&](int t) {
    const int sb = (t & 3) * 24576;
    const int k0 = t * 32;
    g2lds16(&A[(size_t)(m0 + rowS) * Kd + k0 + colS], (char*)lds + sb + tid * 16);
    g2lds16(&A[(size_t)(m0 + rowS + 128) * Kd + k0 + colS],
            (char*)lds + sb + 8192 + tid * 16);
  };
  auto stageB = [&](int t) {
    const int sb = (t & 3) * 24576 + 16384;
    g2lds16(&Bt[(size_t)(n0 + rowS) * Kd + t * 32 + colS],
            (char*)lds + sb + tid * 16);
  };

  floatx4 acc[4][4] = {};
  short8 af0[2], af1[2], bbA[4], bbB[4];

  // prologue: stage tiles 0..2 (9 loads), drain to tile 0 (WAIT6)
  stageA(0); stageB(0);
  stageA(1); stageB(1);
  stageA(2); stageB(2);
  WAIT6;
  __builtin_amdgcn_s_barrier();
#pragma unroll
  for (int n = 0; n < 4; ++n)
    bbA[n] = *reinterpret_cast<const short8*>(ldsb + boff[n]);
  af0[0] = *reinterpret_cast<const short8*>(ldsb + aoff[0]);
  af0[1] = *reinterpret_cast<const short8*>(ldsb + aoff[1]);

#define PITER(T, CUR, NXT)                                                        \
  {                                                                               \
    const int tbR = ((T) & 3) * 24576;                                            \
    af1[0] = *reinterpret_cast<const short8*>(ldsb + tbR + aoff[2]);              \
    af1[1] = *reinterpret_cast<const short8*>(ldsb + tbR + aoff[3]);              \
    __builtin_amdgcn_s_setprio(1);                                                \
    _Pragma("unroll") for (int m = 0; m < 2; ++m)                                 \
        _Pragma("unroll") for (int n = 0; n < 4; ++n)                             \
            acc[m][n] = __builtin_amdgcn_mfma_f32_16x16x32_bf16(                  \
                af0[m], CUR[n], acc[m][n], 0, 0, 0);                              \
    __builtin_amdgcn_s_setprio(0);                                                \
    if ((T) + 3 < NT) { stageA((T) + 3); stageB((T) + 3); }                       \
    if ((T) < NT - 3) { WAIT6; }                                                  \
    else if ((T) == NT - 3) { WAIT3; }                                            \
    else if ((T) == NT - 2) { WAIT0; }                                            \
    asm volatile("s_waitcnt lgkmcnt(0)" ::: "memory");                            \
    __builtin_amdgcn_s_barrier();                                                 \
    if ((T) + 1 < NT) {                                                           \
      const int tbN = (((T) + 1) & 3) * 24576;                                    \
      _Pragma("unroll") for (int n = 0; n < 4; ++n)                               \
          NXT[n] = *reinterpret_cast<const short8*>(ldsb + tbN + boff[n]);        \
      af0[0] = *reinterpret_cast<const short8*>(ldsb + tbN + aoff[0]);            \
      af0[1] = *reinterpret_cast<const short8*>(ldsb + tbN + aoff[1]);            \
    }                                                                             \
    __builtin_amdgcn_s_setprio(1);                                                \
    _Pragma("unroll") for (int m = 0; m < 2; ++m)                                 \
        _Pragma("unroll") for (int n = 0; n < 4; ++n)                             \
            acc[2 + m][n] = __builtin_amdgcn_mfma_f32_16x16x32_bf16(              \
                af1[m], CUR[n], acc[2 + m][n], 0, 0, 0);                          \
    __builtin_amdgcn_s_setprio(0);                                                \
  }

  for (int t = 0; t < NT; t += 2) {
    PITER(t, bbA, bbB);
    PITER(t + 1, bbB, bbA);
  }
#undef PITER

  // epilogue: bias + f32 store
  const int r4 = r4h * 4;
#pragma unroll
  for (int m = 0; m < 4; ++m) {
#pragma unroll
    for (int n = 0; n < 4; ++n) {
      const int gn = n0 + wc * 64 + n * 16 + cl;
      const float bs = bias[gn];
#pragma unroll
      for (int r = 0; r < 4; ++r) {
        const int gm = m0 + wr * 64 + m * 16 + r4 + r;
        outF[(size_t)gm * Nd + gn] = acc[m][n][r] + bs;
      }
    }
  }
}

// ---------------------------------------------------------------- flash attention
// KVBLK=64: ring of 3 KV LDS buffers (16KB each) staged 2 tiles ahead; ONE raw
// s_barrier + ONE counted vmcnt per 64 keys. Swapped QK^T via mfma_32x32x16 in
// two independent 32-key halves. FIXED-max softmax: scores bounded, accumulator
// initialized to -16 (C-operand, free) -> ex2 directly, no max tracking or
// rescale. Diagonal tile: even waves skip the fully-masked upper half.
__global__ __launch_bounds__(256) void attn_kernel(
    const short* __restrict__ Q, const short* __restrict__ Kw,
    const short* __restrict__ Vt, short* __restrict__ Y) {
  __shared__ short lds[3][8192];  // per buf: K 4096 shorts + V 2x2048 shorts
  const int tid = threadIdx.x, l = tid & 63, w = tid >> 6;
  const int ql = l & 31, hi = l >> 5;
  const int bh = blockIdx.x;
  const int qb = 15 - (int)blockIdx.y;
  const int q0w = qb * 128 + w * 32;       // this wave's first query row
  const int jlast = 2 * qb + (w >> 1);     // last KV tile this wave needs
  const int nj = 2 * qb + 2;               // KV tiles staged by the block (>=2)

  short8 qf[4];
  {
    const size_t qbase = ((size_t)bh * T_ + q0w + ql) * HD_;
#pragma unroll
    for (int s = 0; s < 4; ++s)
      qf[s] = *reinterpret_cast<const short8*>(&Q[qbase + s * 16 + hi * 8]);
  }

  // hoisted LDS read offsets (shorts)
  int koffs[4], voffs[4];
#pragma unroll
  for (int s = 0; s < 4; ++s)
    koffs[s] = ql * 64 + (((2 * s + hi) ^ (ql & 7)) * 8);
#pragma unroll
  for (int s2 = 0; s2 < 2; ++s2)
#pragma unroll
    for (int h = 0; h < 2; ++h) {
      int r = 16 * h + (ql >> 1);
      int lc = (ql & 1) * 4 + 2 * s2 + hi;
      voffs[s2 * 2 + h] = r * 64 + ((lc ^ (r & 7)) * 8);
    }

  // staging pointers (advance per tile)
  const int rowSt = tid >> 3, pSt = tid & 7;
  const int gkSt = pSt ^ (rowSt & 7);
  const int dvSt = 2 * rowSt + (gkSt >> 2), kcSt = gkSt & 3;
  const short* kg0 = &Kw[((size_t)bh * T_ + rowSt) * HD_ + gkSt * 8];
  const short* kg1 = &Kw[((size_t)bh * T_ + rowSt + 32) * HD_ + gkSt * 8];
  const short* vg0 = &Vt[((size_t)bh * HD_ + dvSt) * T_ + kcSt * 8];
  const short* vg1 = vg0 + 32;

  floatx16 o0 = {}, o1 = {};
  float l_run = 0.f;

#define STAGE_KV(buf)                                   \
  {                                                     \
    g2lds16(kg0, &lds[buf][0] + tid * 8);               \
    g2lds16(kg1, &lds[buf][2048] + tid * 8);            \
    g2lds16(vg0, &lds[buf][4096] + tid * 8);            \
    g2lds16(vg1, &lds[buf][6144] + tid * 8);            \
    kg0 += 64 * HD_; kg1 += 64 * HD_;                   \
    vg0 += 64; vg1 += 64;                               \
  }

  auto do_half = [&](const short* bK, const short* bV, int koff_add, int vbase,
                     bool domask) {
    floatx16 sx;
#pragma unroll
    for (int r = 0; r < 16; ++r) sx[r] = -16.0f;  // fixed-max offset
#pragma unroll
    for (int s = 0; s < 4; ++s) {
      short8 ka = *reinterpret_cast<const short8*>(bK + koff_add + koffs[s]);
      sx = __builtin_amdgcn_mfma_f32_32x32x16_bf16(ka, qf[s], sx, 0, 0, 0);
    }
    if (domask) {
#pragma unroll
      for (int r = 0; r < 16; ++r) {
        int kb = (r & 3) + 8 * (r >> 2) + 4 * hi;
        if (kb > ql) sx[r] = -1e30f;
      }
    }
#pragma unroll
    for (int r = 0; r < 16; ++r) sx[r] = ex2(sx[r]);
    float a0 = (sx[0] + sx[1]) + (sx[2] + sx[3]);
    float a1 = (sx[4] + sx[5]) + (sx[6] + sx[7]);
    float a2 = (sx[8] + sx[9]) + (sx[10] + sx[11]);
    float a3 = (sx[12] + sx[13]) + (sx[14] + sx[15]);
    l_run += (a0 + a1) + (a2 + a3);
    unsigned pw[8];
#pragma unroll
    for (int i = 0; i < 8; ++i) pw[i] = cvtpk(sx[2 * i], sx[2 * i + 1]);
#pragma unroll
    for (int s2 = 0; s2 < 2; ++s2) {
      unsigned a0w = pw[4 * s2 + 0], a1w = pw[4 * s2 + 1];
      unsigned a2w = pw[4 * s2 + 2], a3w = pw[4 * s2 + 3];
      asm("v_permlane32_swap_b32 %0, %1" : "+v"(a0w), "+v"(a2w));
      asm("v_permlane32_swap_b32 %0, %1" : "+v"(a1w), "+v"(a3w));
      union { unsigned u[4]; short8 s8; } pb;
      pb.u[0] = a0w; pb.u[1] = a1w; pb.u[2] = a2w; pb.u[3] = a3w;
#pragma unroll
      for (int h = 0; h < 2; ++h) {
        short8 va = *reinterpret_cast<const short8*>(bV + vbase + voffs[s2 * 2 + h]);
        if (h == 0) o0 = __builtin_amdgcn_mfma_f32_32x32x16_bf16(va, pb.s8, o0, 0, 0, 0);
        else        o1 = __builtin_amdgcn_mfma_f32_32x32x16_bf16(va, pb.s8, o1, 0, 0, 0);
      }
    }
  };

  STAGE_KV(0);
  STAGE_KV(1);

  for (int j = 0; j < nj; ++j) {
    if (j == nj - 1) { WAIT0; } else { WAIT4; }
    __builtin_amdgcn_s_barrier();
    if (j + 2 < nj) STAGE_KV((j + 2) % 3);

    if (j <= jlast) {
      const short* bK = &lds[j % 3][0];
      const short* bV = &lds[j % 3][4096];
      const bool diag = (j == jlast);
      do_half(bK, bV, 0, 0, diag && ((w & 1) == 0));
      if (!diag || (w & 1))
        do_half(bK, bV, 2048, 2048, diag);
    }
  }

  l_run += __shfl_xor(l_run, 32);
  float inv = 1.0f / l_run;
#pragma unroll
  for (int r = 0; r < 16; ++r) { o0[r] *= inv; o1[r] *= inv; }
  __syncthreads();
  short* tb2 = &lds[0][0] + w * 2048;
#pragma unroll
  for (int h = 0; h < 2; ++h) {
#pragma unroll
    for (int qd = 0; qd < 4; ++qd) {
      int dbase = 32 * h + 8 * qd + 4 * hi;
      uint2 v;
      v.x = h == 0 ? cvtpk(o0[4 * qd], o0[4 * qd + 1]) : cvtpk(o1[4 * qd], o1[4 * qd + 1]);
      v.y = h == 0 ? cvtpk(o0[4 * qd + 2], o0[4 * qd + 3]) : cvtpk(o1[4 * qd + 2], o1[4 * qd + 3]);
      int byte = (ql * 128 + dbase * 2) ^ ((ql & 7) << 4);
      *reinterpret_cast<uint2*>(reinterpret_cast<char*>(tb2) + byte) = v;
    }
  }
  __syncthreads();
  const int bb = bh >> 4, hh = bh & 15;
#pragma unroll
  for (int p = 0; p < 4; ++p) {
    int c = p * 64 + l;
    int q = c >> 3, dc = c & 7;
    int byte = (q * 128 + dc * 16) ^ ((q & 7) << 4);
    short8 v = *reinterpret_cast<const short8*>(reinterpret_cast<const char*>(tb2) + byte);
    *reinterpret_cast<short8*>(
        &Y[((size_t)(bb * T_ + q0w + q)) * C_ + hh * 64 + dc * 8]) = v;
  }
#undef STAGE_KV
}

// ---------------------------------------------------------------- launch
extern "C" void kernel_launch(void* const* d_in, const int* in_sizes, int n_in,
                              void* d_out, int out_size, void* d_ws, size_t ws_size,
                              hipStream_t stream) {
  const float* x      = (const float*)d_in[0];
  const float* freqs  = (const float*)d_in[1];
  const float* W_attn = (const float*)d_in[2];
  const float* b_attn = (const float*)d_in[3];
  const float* W_proj = (const float*)d_in[4];
  const float* b_proj = (const float*)d_in[5];
  float* out = (float*)d_out;
  char* ws = (char*)d_ws;

  const size_t SZ_QKV = (size_t)BH_ * T_ * HD_ * 2;  // 33554432 bytes each
  short* Qw  = (short*)(ws);
  short* Kw  = (short*)(ws + SZ_QKV);
  short* Vt  = (short*)(ws + 2 * SZ_QKV);
  short* Xb  = (short*)(ws + 3 * SZ_QKV);            // x bf16, later reused as Y
  short* WtA = (short*)(ws + 4 * SZ_QKV);            // [3072][1024] bf16
  short* WtP = (short*)(ws + 4 * SZ_QKV + 6291456);  // [1024][1024] bf16
  float2* trig = (float2*)(ws + 4 * SZ_QKV + 6291456 + 2097152);  // [2048][32]

  cvt_x_kernel<<<(M_ * C_ / 8 + 255) / 256, 256, 0, stream>>>(x, Xb, M_ * C_ / 8);
  transpose_w_kernel<<<dim3(3 * C_ / 64, C_ / 64), 256, 0, stream>>>(W_attn, WtA, C_, 3 * C_);
  transpose_w_kernel<<<dim3(C_ / 64, C_ / 64), 256, 0, stream>>>(W_proj, WtP, C_, C_);
  trig_kernel<<<(T_ * 32 + 255) / 256, 256, 0, stream>>>(freqs, trig, T_ * 32);

  gemm8_kernel<<<dim3((3 * C_ / 256) * (M_ / 256)), 512, 0, stream>>>(
      Xb, WtA, b_attn, 3 * C_, 3 * C_ / 256, Qw, Kw, Vt, trig);

  attn_kernel<<<dim3(BH_, 16), 256, 0, stream>>>(Qw, Kw, Vt, Xb);

  gemm_proj_kernel<<<dim3((C_ / 128) * (M_ / 256)), 512, 0, stream>>>(
      Xb, WtP, b_proj, out);
}